// Round 1
// baseline (269.058 us; speedup 1.0000x reference)
//
#include <hip/hip_runtime.h>
#include <hip/hip_bf16.h>

// Layer sizes: 500 -> 400 -> 300 -> 200 -> 100
// ws layout (u32 indices): MA[500*16] @0, MB[400*16] @8000, V @14400,
// IDX @14912, HSEL @15424, RSUM @15936   (total ~66 KB)

#define MS 16  // mask row stride in u32 words

__device__ __forceinline__ float maskdot(const unsigned* __restrict__ mrow, int W,
                                         const float* __restrict__ sv) {
    float acc = 0.f;
    for (int w = 0; w < W; ++w) {
        unsigned m = mrow[w];
        while (m) {
            int b = __ffs(m) - 1;
            m &= m - 1;
            acc += sv[(w << 5) + b];
        }
    }
    return acc;
}

__device__ __forceinline__ float wave_reduce(float v) {
    for (int o = 32; o; o >>= 1) v += __shfl_down(v, o);
    return v;
}

// v[row] = dot(h[row,:], Wt)   and build bitmask of g row.
__global__ void k_dot(const float* __restrict__ h, const float* __restrict__ Wt,
                      const float* __restrict__ g, float* __restrict__ V,
                      unsigned* __restrict__ MA) {
    int row = blockIdx.x;
    int t = threadIdx.x;  // 512 threads
    const float4* h4 = (const float4*)(h + (size_t)row * 32768);
    const float4* w4 = (const float4*)Wt;
    float acc = 0.f;
    for (int j = t; j < 8192; j += 512) {
        float4 a = h4[j], b = w4[j];
        acc = fmaf(a.x, b.x, acc);
        acc = fmaf(a.y, b.y, acc);
        acc = fmaf(a.z, b.z, acc);
        acc = fmaf(a.w, b.w, acc);
    }
    acc = wave_reduce(acc);
    __shared__ float red[8];
    if ((t & 63) == 0) red[t >> 6] = acc;
    __syncthreads();
    if (t == 0) {
        float s = 0.f;
        for (int i = 0; i < 8; ++i) s += red[i];
        V[row] = s;
    }
    if (t < 16) {
        unsigned bits = 0;
        for (int b = 0; b < 32; ++b) {
            int c = (t << 5) + b;
            if (c < 500 && g[row * 500 + c] != 0.f) bits |= 1u << b;
        }
        MA[row * MS + t] = bits;
    }
}

// h_top = relu(g@v + b_top); scores0 = sigmoid(relu((g@h_top)*Wp0 + bp0)); top-k.
__global__ void k_top(const unsigned* __restrict__ MA, const float* __restrict__ V,
                      const float* __restrict__ b_top, const float* __restrict__ Wp0,
                      const float* __restrict__ bp0, int* __restrict__ IDX,
                      float* __restrict__ HSEL, float* __restrict__ out) {
    __shared__ float sv[512], sh[512], ssc[512];
    int t = threadIdx.x;  // 512
    if (t < 500) sv[t] = V[t];
    __syncthreads();
    if (t < 500) {
        float acc = maskdot(MA + t * MS, 16, sv);
        float hv = fmaxf(acc + b_top[0], 0.f);
        sh[t] = hv;
        out[t] = hv;
    }
    __syncthreads();
    if (t < 500) {
        float acc = maskdot(MA + t * MS, 16, sh);
        float x = fmaxf(acc * Wp0[0] + bp0[0], 0.f);
        ssc[t] = 1.f / (1.f + expf(-x));
    }
    __syncthreads();
    if (t < 500) {
        float my = ssc[t];
        int rank = 0;
        for (int j = 0; j < 500; ++j) {
            float sj = ssc[j];
            rank += (sj > my) || (sj == my && j < t);
        }
        if (rank < 400) {
            IDX[rank] = t;
            HSEL[rank] = sh[t] * my;
        }
    }
}

// 2-hop connectivity of current graph, restricted to selected rows/cols; row popcounts.
// 4 waves/block, one selected row per wave. grid = kk/4.
__global__ void k_twohop(const unsigned* __restrict__ Mcur, unsigned* __restrict__ Mnew,
                         const int* __restrict__ IDX, float* __restrict__ RSUM,
                         int n, int kk, int Wcur) {
    int wid = threadIdx.x >> 6, lane = threadIdx.x & 63;
    int r = blockIdx.x * 4 + wid;
    int i = IDX[r];
    __shared__ unsigned srow[4][16];
    __shared__ unsigned un2[4][16];
    if (lane < 16) {
        srow[wid][lane] = (lane < Wcur) ? Mcur[i * MS + lane] : 0u;
        un2[wid][lane] = 0u;
    }
    __syncthreads();
    int part = lane >> 4, w = lane & 15;
    if (w < Wcur) {
        unsigned acc = 0;
        for (int k = part; k < n; k += 4) {
            if ((srow[wid][k >> 5] >> (k & 31)) & 1u) acc |= Mcur[k * MS + w];
        }
        atomicOr(&un2[wid][w], acc);
    }
    __syncthreads();
    unsigned long long cnt = 0;
    for (int c0 = 0; c0 < kk; c0 += 64) {
        int c = c0 + lane;
        int ok = 0;
        if (c < kk) {
            int j = IDX[c];
            ok = (un2[wid][j >> 5] >> (j & 31)) & 1;
        }
        unsigned long long bits = __ballot(ok);
        if (lane == 0) {
            Mnew[r * MS + (c0 >> 5)] = (unsigned)bits;
            Mnew[r * MS + (c0 >> 5) + 1] = (unsigned)(bits >> 32);
        }
        cnt += __popcll(bits);
    }
    if (lane == 0) RSUM[r] = (float)cnt;
}

// down-GCN + (optionally) next-layer scores + top-k.
__global__ void k_mid(const unsigned* __restrict__ M, const float* __restrict__ RSUM,
                      int* __restrict__ IDX, float* __restrict__ HSEL,
                      const float* __restrict__ Wd, const float* __restrict__ bd,
                      const float* __restrict__ Wp, const float* __restrict__ bp,
                      float* __restrict__ out_seg, int kk, int knext) {
    __shared__ float su[512], shd[512], srs[512], ssc[512];
    int t = threadIdx.x;  // 512
    int W = (kk + 31) >> 5;
    if (t < kk) {
        float rs = RSUM[t];
        srs[t] = rs;
        su[t] = HSEL[t] * Wd[t] / rs;
    }
    __syncthreads();
    if (t < kk) {
        float acc = maskdot(M + t * MS, W, su);
        float hv = fmaxf(acc + bd[0], 0.f);
        shd[t] = hv;
        out_seg[t] = hv;
    }
    __syncthreads();
    if (knext == 0) return;
    if (t < kk) su[t] = shd[t] / srs[t];
    __syncthreads();
    if (t < kk) {
        float acc = maskdot(M + t * MS, W, su);
        float x = fmaxf(acc * Wp[0] + bp[0], 0.f);
        ssc[t] = 1.f / (1.f + expf(-x));
    }
    __syncthreads();
    if (t < kk) {
        float my = ssc[t];
        int rank = 0;
        for (int j = 0; j < kk; ++j) {
            float sj = ssc[j];
            rank += (sj > my) || (sj == my && j < t);
        }
        if (rank < knext) {
            IDX[rank] = t;
            HSEL[rank] = shd[t] * my;
        }
    }
}

extern "C" void kernel_launch(void* const* d_in, const int* in_sizes, int n_in,
                              void* d_out, int out_size, void* d_ws, size_t ws_size,
                              hipStream_t stream) {
    const float* g = (const float*)d_in[0];
    const float* h = (const float*)d_in[1];
    const float* W_top = (const float*)d_in[2];
    const float* b_top = (const float*)d_in[3];
    const float* Wp[4], *bp[4], *Wd[4], *bd[4];
    for (int i = 0; i < 4; ++i) {
        Wp[i] = (const float*)d_in[4 + 4 * i];
        bp[i] = (const float*)d_in[5 + 4 * i];
        Wd[i] = (const float*)d_in[6 + 4 * i];
        bd[i] = (const float*)d_in[7 + 4 * i];
    }
    float* out = (float*)d_out;

    unsigned* wsu = (unsigned*)d_ws;
    unsigned* MA = wsu + 0;       // 500*16
    unsigned* MB = wsu + 8000;    // 400*16
    float* V = (float*)(wsu + 14400);
    int* IDX = (int*)(wsu + 14912);
    float* HSEL = (float*)(wsu + 15424);
    float* RSUM = (float*)(wsu + 15936);

    k_dot<<<500, 512, 0, stream>>>(h, W_top, g, V, MA);
    k_top<<<1, 512, 0, stream>>>(MA, V, b_top, Wp[0], bp[0], IDX, HSEL, out);

    // layer 0: n=500 -> kk=400
    k_twohop<<<100, 256, 0, stream>>>(MA, MB, IDX, RSUM, 500, 400, 16);
    k_mid<<<1, 512, 0, stream>>>(MB, RSUM, IDX, HSEL, Wd[0], bd[0], Wp[1], bp[1],
                                 out + 500, 400, 300);
    // layer 1: n=400 -> kk=300
    k_twohop<<<75, 256, 0, stream>>>(MB, MA, IDX, RSUM, 400, 300, 13);
    k_mid<<<1, 512, 0, stream>>>(MA, RSUM, IDX, HSEL, Wd[1], bd[1], Wp[2], bp[2],
                                 out + 900, 300, 200);
    // layer 2: n=300 -> kk=200
    k_twohop<<<50, 256, 0, stream>>>(MA, MB, IDX, RSUM, 300, 200, 10);
    k_mid<<<1, 512, 0, stream>>>(MB, RSUM, IDX, HSEL, Wd[2], bd[2], Wp[3], bp[3],
                                 out + 1200, 200, 100);
    // layer 3: n=200 -> kk=100
    k_twohop<<<25, 256, 0, stream>>>(MB, MA, IDX, RSUM, 200, 100, 7);
    k_mid<<<1, 512, 0, stream>>>(MA, RSUM, IDX, HSEL, Wd[3], bd[3], nullptr, nullptr,
                                 out + 1400, 100, 0);
}

// Round 2
// 180.734 us; speedup vs baseline: 1.4887x; 1.4887x over previous
//
#include <hip/hip_runtime.h>
#include <hip/hip_bf16.h>

// Layer sizes: 500 -> 400 -> 300 -> 200 -> 100
// ws layout (u32 indices): MA[500*16] @0, MB[400*16] @8000, V @14400,
// IDX @14912, HSEL @15424, RSUM @15936   (total ~66 KB)

#define MS 16  // mask row stride in u32 words

// Dense fixed-trip-count masked dot: compiler unrolls + pipelines.
// sv[] reads are lane-invariant (broadcast, conflict-free). Select (not
// multiply) so uninitialized sv slots beyond n never poison the sum.
__device__ __forceinline__ float maskdot(const unsigned* __restrict__ mrow, int W,
                                         const float* __restrict__ sv) {
    float acc = 0.f;
    for (int w = 0; w < W; ++w) {
        unsigned m = mrow[w];
        const float* p = sv + (w << 5);
#pragma unroll
        for (int b = 0; b < 32; ++b) {
            acc += ((m >> b) & 1u) ? p[b] : 0.f;
        }
    }
    return acc;
}

__device__ __forceinline__ float wave_reduce(float v) {
    for (int o = 32; o; o >>= 1) v += __shfl_down(v, o);
    return v;
}

// v[row] = dot(h[row,:], Wt)   and build bitmask of g row.
__global__ void k_dot(const float* __restrict__ h, const float* __restrict__ Wt,
                      const float* __restrict__ g, float* __restrict__ V,
                      unsigned* __restrict__ MA) {
    int row = blockIdx.x;
    int t = threadIdx.x;  // 512 threads
    const float4* h4 = (const float4*)(h + (size_t)row * 32768);
    const float4* w4 = (const float4*)Wt;
    float acc = 0.f;
    for (int j = t; j < 8192; j += 512) {
        float4 a = h4[j], b = w4[j];
        acc = fmaf(a.x, b.x, acc);
        acc = fmaf(a.y, b.y, acc);
        acc = fmaf(a.z, b.z, acc);
        acc = fmaf(a.w, b.w, acc);
    }
    acc = wave_reduce(acc);
    __shared__ float red[8];
    if ((t & 63) == 0) red[t >> 6] = acc;
    __syncthreads();
    if (t == 0) {
        float s = 0.f;
        for (int i = 0; i < 8; ++i) s += red[i];
        V[row] = s;
    }
    if (t < 16) {
        unsigned bits = 0;
        for (int b = 0; b < 32; ++b) {
            int c = (t << 5) + b;
            if (c < 500 && g[row * 500 + c] != 0.f) bits |= 1u << b;
        }
        MA[row * MS + t] = bits;
    }
}

// h_top = relu(g@v + b_top); scores0 = sigmoid(relu((g@h_top)*Wp0 + bp0)); top-k.
__global__ void k_top(const unsigned* __restrict__ MA, const float* __restrict__ V,
                      const float* __restrict__ b_top, const float* __restrict__ Wp0,
                      const float* __restrict__ bp0, int* __restrict__ IDX,
                      float* __restrict__ HSEL, float* __restrict__ out) {
    __shared__ float sv[512], sh[512], ssc[512];
    int t = threadIdx.x;  // 512
    sv[t] = (t < 500) ? V[t] : 0.f;
    sh[t] = 0.f;
    ssc[t] = 0.f;
    __syncthreads();
    if (t < 500) {
        float acc = maskdot(MA + t * MS, 16, sv);
        float hv = fmaxf(acc + b_top[0], 0.f);
        sh[t] = hv;
        out[t] = hv;
    }
    __syncthreads();
    if (t < 500) {
        float acc = maskdot(MA + t * MS, 16, sh);
        float x = fmaxf(acc * Wp0[0] + bp0[0], 0.f);
        ssc[t] = 1.f / (1.f + expf(-x));
    }
    __syncthreads();
    if (t < 500) {
        float my = ssc[t];
        int rank = 0;
#pragma unroll 4
        for (int j = 0; j < 500; ++j) {
            float sj = ssc[j];
            rank += (sj > my) || (sj == my && j < t);
        }
        if (rank < 400) {
            IDX[rank] = t;
            HSEL[rank] = sh[t] * my;
        }
    }
}

// 2-hop connectivity of current graph, restricted to selected rows/cols; row popcounts.
// 4 waves/block, one selected row per wave. grid = kk/4.
__global__ void k_twohop(const unsigned* __restrict__ Mcur, unsigned* __restrict__ Mnew,
                         const int* __restrict__ IDX, float* __restrict__ RSUM,
                         int n, int kk, int Wcur) {
    int wid = threadIdx.x >> 6, lane = threadIdx.x & 63;
    int r = blockIdx.x * 4 + wid;
    int i = IDX[r];
    __shared__ unsigned srow[4][16];
    __shared__ unsigned un2[4][16];
    if (lane < 16) {
        srow[wid][lane] = (lane < Wcur) ? Mcur[i * MS + lane] : 0u;
        un2[wid][lane] = 0u;
    }
    __syncthreads();
    int part = lane >> 4, w = lane & 15;
    if (w < Wcur) {
        unsigned acc = 0;
        for (int k = part; k < n; k += 4) {
            // unconditional load + AND-mask so loads pipeline (no branch serialization)
            unsigned sel = ((srow[wid][k >> 5] >> (k & 31)) & 1u) ? 0xffffffffu : 0u;
            acc |= Mcur[k * MS + w] & sel;
        }
        atomicOr(&un2[wid][w], acc);
    }
    __syncthreads();
    unsigned long long cnt = 0;
    for (int c0 = 0; c0 < kk; c0 += 64) {
        int c = c0 + lane;
        int ok = 0;
        if (c < kk) {
            int j = IDX[c];
            ok = (un2[wid][j >> 5] >> (j & 31)) & 1;
        }
        unsigned long long bits = __ballot(ok);
        if (lane == 0) {
            Mnew[r * MS + (c0 >> 5)] = (unsigned)bits;
            Mnew[r * MS + (c0 >> 5) + 1] = (unsigned)(bits >> 32);
        }
        cnt += __popcll(bits);
    }
    if (lane == 0) RSUM[r] = (float)cnt;
}

// down-GCN + (optionally) next-layer scores + top-k.
__global__ void k_mid(const unsigned* __restrict__ M, const float* __restrict__ RSUM,
                      int* __restrict__ IDX, float* __restrict__ HSEL,
                      const float* __restrict__ Wd, const float* __restrict__ bd,
                      const float* __restrict__ Wp, const float* __restrict__ bp,
                      float* __restrict__ out_seg, int kk, int knext) {
    __shared__ float su[512], shd[512], srs[512], ssc[512];
    int t = threadIdx.x;  // 512
    int W = (kk + 31) >> 5;
    su[t] = 0.f;
    shd[t] = 0.f;
    srs[t] = 1.f;
    ssc[t] = 0.f;
    __syncthreads();
    if (t < kk) {
        float rs = RSUM[t];
        srs[t] = rs;
        su[t] = HSEL[t] * Wd[t] / rs;
    }
    __syncthreads();
    if (t < kk) {
        float acc = maskdot(M + t * MS, W, su);
        float hv = fmaxf(acc + bd[0], 0.f);
        shd[t] = hv;
        out_seg[t] = hv;
    }
    __syncthreads();
    if (knext == 0) return;
    if (t < kk) su[t] = shd[t] / srs[t];
    __syncthreads();
    if (t < kk) {
        float acc = maskdot(M + t * MS, W, su);
        float x = fmaxf(acc * Wp[0] + bp[0], 0.f);
        ssc[t] = 1.f / (1.f + expf(-x));
    }
    __syncthreads();
    if (t < kk) {
        float my = ssc[t];
        int rank = 0;
#pragma unroll 4
        for (int j = 0; j < kk; ++j) {
            float sj = ssc[j];
            rank += (sj > my) || (sj == my && j < t);
        }
        if (rank < knext) {
            IDX[rank] = t;
            HSEL[rank] = shd[t] * my;
        }
    }
}

extern "C" void kernel_launch(void* const* d_in, const int* in_sizes, int n_in,
                              void* d_out, int out_size, void* d_ws, size_t ws_size,
                              hipStream_t stream) {
    const float* g = (const float*)d_in[0];
    const float* h = (const float*)d_in[1];
    const float* W_top = (const float*)d_in[2];
    const float* b_top = (const float*)d_in[3];
    const float* Wp[4], *bp[4], *Wd[4], *bd[4];
    for (int i = 0; i < 4; ++i) {
        Wp[i] = (const float*)d_in[4 + 4 * i];
        bp[i] = (const float*)d_in[5 + 4 * i];
        Wd[i] = (const float*)d_in[6 + 4 * i];
        bd[i] = (const float*)d_in[7 + 4 * i];
    }
    float* out = (float*)d_out;

    unsigned* wsu = (unsigned*)d_ws;
    unsigned* MA = wsu + 0;       // 500*16
    unsigned* MB = wsu + 8000;    // 400*16
    float* V = (float*)(wsu + 14400);
    int* IDX = (int*)(wsu + 14912);
    float* HSEL = (float*)(wsu + 15424);
    float* RSUM = (float*)(wsu + 15936);

    k_dot<<<500, 512, 0, stream>>>(h, W_top, g, V, MA);
    k_top<<<1, 512, 0, stream>>>(MA, V, b_top, Wp[0], bp[0], IDX, HSEL, out);

    // layer 0: n=500 -> kk=400
    k_twohop<<<100, 256, 0, stream>>>(MA, MB, IDX, RSUM, 500, 400, 16);
    k_mid<<<1, 512, 0, stream>>>(MB, RSUM, IDX, HSEL, Wd[0], bd[0], Wp[1], bp[1],
                                 out + 500, 400, 300);
    // layer 1: n=400 -> kk=300
    k_twohop<<<75, 256, 0, stream>>>(MB, MA, IDX, RSUM, 400, 300, 13);
    k_mid<<<1, 512, 0, stream>>>(MA, RSUM, IDX, HSEL, Wd[1], bd[1], Wp[2], bp[2],
                                 out + 900, 300, 200);
    // layer 2: n=300 -> kk=200
    k_twohop<<<50, 256, 0, stream>>>(MA, MB, IDX, RSUM, 300, 200, 10);
    k_mid<<<1, 512, 0, stream>>>(MB, RSUM, IDX, HSEL, Wd[2], bd[2], Wp[3], bp[3],
                                 out + 1200, 200, 100);
    // layer 3: n=200 -> kk=100
    k_twohop<<<25, 256, 0, stream>>>(MB, MA, IDX, RSUM, 200, 100, 7);
    k_mid<<<1, 512, 0, stream>>>(MA, RSUM, IDX, HSEL, Wd[3], bd[3], nullptr, nullptr,
                                 out + 1400, 100, 0);
}

// Round 3
// 136.272 us; speedup vs baseline: 1.9744x; 1.3263x over previous
//
#include <hip/hip_runtime.h>
#include <hip/hip_bf16.h>

// Layer sizes: 500 -> 400 -> 300 -> 200 -> 100
// ws layout (u32 indices): MA[500*16] @0, MB[400*16] @8000, V @14400,
// IDX @14912, HSEL @15424, RSUM @15936   (total ~66 KB)

#define MS 16  // mask row stride in u32 words

// Branchless masked accumulate: bit k of m sign-extended to 0/-1, ANDed with
// the value's bits. Adding +0.0f is exact; sv slots beyond n are zeroed.
__device__ __forceinline__ float bitsel(unsigned m, int k, float v) {
    int s = ((int)(m << (31 - k))) >> 31;  // bfe_i32: 0 or 0xFFFFFFFF
    return __int_as_float(s & __float_as_int(v));
}

// Partial masked dot over words [w0, w1) with 4 independent accumulators and
// float4 (ds_read_b128) broadcast reads.
__device__ __forceinline__ float maskdot_part(const unsigned* __restrict__ mrow,
                                              int w0, int w1,
                                              const float* __restrict__ sv) {
    float a0 = 0.f, a1 = 0.f, a2 = 0.f, a3 = 0.f;
    for (int w = w0; w < w1; ++w) {
        unsigned m = mrow[w];
        const float4* p4 = (const float4*)(sv + (w << 5));
#pragma unroll
        for (int q = 0; q < 8; ++q) {
            float4 v = p4[q];
            a0 += bitsel(m, 4 * q + 0, v.x);
            a1 += bitsel(m, 4 * q + 1, v.y);
            a2 += bitsel(m, 4 * q + 2, v.z);
            a3 += bitsel(m, 4 * q + 3, v.w);
        }
    }
    return (a0 + a1) + (a2 + a3);
}

// Partial stable-rank over j in [j0, j1): count (sj > my) || (sj == my && j < r).
__device__ __forceinline__ int rank_part(const float* __restrict__ ssc, int j0,
                                         int j1, float my, int r) {
    int r0 = 0, r1 = 0, r2 = 0, r3 = 0;
    for (int j = j0; j < j1; j += 4) {
        float4 v = *(const float4*)(ssc + j);
        r0 += (v.x > my) || (v.x == my && (j + 0) < r);
        r1 += (v.y > my) || (v.y == my && (j + 1) < r);
        r2 += (v.z > my) || (v.z == my && (j + 2) < r);
        r3 += (v.w > my) || (v.w == my && (j + 3) < r);
    }
    return (r0 + r1) + (r2 + r3);
}

__device__ __forceinline__ float wave_reduce(float v) {
    for (int o = 32; o; o >>= 1) v += __shfl_down(v, o);
    return v;
}

// v[row] = dot(h[row,:], Wt)   and build bitmask of g row.
__global__ void k_dot(const float* __restrict__ h, const float* __restrict__ Wt,
                      const float* __restrict__ g, float* __restrict__ V,
                      unsigned* __restrict__ MA) {
    int row = blockIdx.x;
    int t = threadIdx.x;  // 512 threads
    const float4* h4 = (const float4*)(h + (size_t)row * 32768);
    const float4* w4 = (const float4*)Wt;
    float acc = 0.f;
    for (int j = t; j < 8192; j += 512) {
        float4 a = h4[j], b = w4[j];
        acc = fmaf(a.x, b.x, acc);
        acc = fmaf(a.y, b.y, acc);
        acc = fmaf(a.z, b.z, acc);
        acc = fmaf(a.w, b.w, acc);
    }
    acc = wave_reduce(acc);
    __shared__ float red[8];
    if ((t & 63) == 0) red[t >> 6] = acc;
    __syncthreads();
    if (t == 0) {
        float s = 0.f;
        for (int i = 0; i < 8; ++i) s += red[i];
        V[row] = s;
    }
    if (t < 16) {
        unsigned bits = 0;
        for (int b = 0; b < 32; ++b) {
            int c = (t << 5) + b;
            if (c < 500 && g[row * 500 + c] != 0.f) bits |= 1u << b;
        }
        MA[row * MS + t] = bits;
    }
}

// h_top = relu(g@v + b_top); scores0 = sigmoid(relu((g@h_top)*Wp0 + bp0)); top-k.
// 1024 threads: row r = t>>1, half = t&1 (split words / rank range).
__global__ void k_top(const unsigned* __restrict__ MA, const float* __restrict__ V,
                      const float* __restrict__ b_top, const float* __restrict__ Wp0,
                      const float* __restrict__ bp0, int* __restrict__ IDX,
                      float* __restrict__ HSEL, float* __restrict__ out) {
    __shared__ float sv[512], sh[512], ssc[512];
    int t = threadIdx.x;
    int r = t >> 1, half = t & 1;
    if (t < 512) {
        sv[t] = (t < 500) ? V[t] : 0.f;
        sh[t] = 0.f;
        ssc[t] = 0.f;
    }
    __syncthreads();
    int w0 = half ? 8 : 0, w1 = half ? 16 : 8;
    if (r < 500) {
        float acc = maskdot_part(MA + r * MS, w0, w1, sv);
        acc += __shfl_xor(acc, 1);
        if (!half) {
            float hv = fmaxf(acc + b_top[0], 0.f);
            sh[r] = hv;
            out[r] = hv;
        }
    }
    __syncthreads();
    if (r < 500) {
        float acc = maskdot_part(MA + r * MS, w0, w1, sh);
        acc += __shfl_xor(acc, 1);
        if (!half) {
            float x = fmaxf(acc * Wp0[0] + bp0[0], 0.f);
            ssc[r] = 1.f / (1.f + expf(-x));
        }
    }
    __syncthreads();
    if (r < 500) {
        float my = ssc[r];
        int rank = rank_part(ssc, half ? 256 : 0, half ? 512 : 256, my, r);
        rank += __shfl_xor(rank, 1);
        if (!half && rank < 400) {
            IDX[rank] = r;
            HSEL[rank] = sh[r] * my;
        }
    }
}

// 2-hop connectivity of current graph, restricted to selected rows/cols; row popcounts.
// 4 waves/block, one selected row per wave. grid = kk/4.
__global__ void k_twohop(const unsigned* __restrict__ Mcur, unsigned* __restrict__ Mnew,
                         const int* __restrict__ IDX, float* __restrict__ RSUM,
                         int n, int kk, int Wcur) {
    int wid = threadIdx.x >> 6, lane = threadIdx.x & 63;
    int r = blockIdx.x * 4 + wid;
    int i = IDX[r];
    __shared__ unsigned srow[4][16];
    __shared__ unsigned un2[4][16];
    if (lane < 16) {
        srow[wid][lane] = (lane < Wcur) ? Mcur[i * MS + lane] : 0u;
        un2[wid][lane] = 0u;
    }
    __syncthreads();
    int part = lane >> 4, w = lane & 15;
    if (w < Wcur) {
        unsigned acc = 0;
        for (int k = part; k < n; k += 4) {
            unsigned sel = ((srow[wid][k >> 5] >> (k & 31)) & 1u) ? 0xffffffffu : 0u;
            acc |= Mcur[k * MS + w] & sel;
        }
        atomicOr(&un2[wid][w], acc);
    }
    __syncthreads();
    unsigned long long cnt = 0;
    for (int c0 = 0; c0 < kk; c0 += 64) {
        int c = c0 + lane;
        int ok = 0;
        if (c < kk) {
            int j = IDX[c];
            ok = (un2[wid][j >> 5] >> (j & 31)) & 1;
        }
        unsigned long long bits = __ballot(ok);
        if (lane == 0) {
            Mnew[r * MS + (c0 >> 5)] = (unsigned)bits;
            Mnew[r * MS + (c0 >> 5) + 1] = (unsigned)(bits >> 32);
        }
        cnt += __popcll(bits);
    }
    if (lane == 0) RSUM[r] = (float)cnt;
}

// down-GCN + (optionally) next-layer scores + top-k. 1024 threads, row-pair split.
__global__ void k_mid(const unsigned* __restrict__ M, const float* __restrict__ RSUM,
                      int* __restrict__ IDX, float* __restrict__ HSEL,
                      const float* __restrict__ Wd, const float* __restrict__ bd,
                      const float* __restrict__ Wp, const float* __restrict__ bp,
                      float* __restrict__ out_seg, int kk, int knext) {
    __shared__ float su[512], shd[512], srs[512], ssc[512];
    int t = threadIdx.x;
    int r = t >> 1, half = t & 1;
    int W = (kk + 31) >> 5;
    int wm = (W + 1) >> 1;
    int w0 = half ? wm : 0, w1 = half ? W : wm;
    if (t < 512) {
        su[t] = 0.f;
        shd[t] = 0.f;
        srs[t] = 1.f;
        ssc[t] = 0.f;
    }
    __syncthreads();
    if (t < kk) {
        float rs = RSUM[t];
        srs[t] = rs;
        su[t] = HSEL[t] * Wd[t] / rs;
    }
    __syncthreads();
    if (r < kk) {
        float acc = maskdot_part(M + r * MS, w0, w1, su);
        acc += __shfl_xor(acc, 1);
        if (!half) {
            float hv = fmaxf(acc + bd[0], 0.f);
            shd[r] = hv;
            out_seg[r] = hv;
        }
    }
    __syncthreads();
    if (knext == 0) return;
    if (t < kk) su[t] = shd[t] / srs[t];
    __syncthreads();
    if (r < kk) {
        float acc = maskdot_part(M + r * MS, w0, w1, su);
        acc += __shfl_xor(acc, 1);
        if (!half) {
            float x = fmaxf(acc * Wp[0] + bp[0], 0.f);
            ssc[r] = 1.f / (1.f + expf(-x));
        }
    }
    __syncthreads();
    if (r < kk) {
        float my = ssc[r];
        int rank = rank_part(ssc, half ? 256 : 0, half ? 512 : 256, my, r);
        rank += __shfl_xor(rank, 1);
        if (!half && rank < knext) {
            IDX[rank] = r;
            HSEL[rank] = shd[r] * my;
        }
    }
}

extern "C" void kernel_launch(void* const* d_in, const int* in_sizes, int n_in,
                              void* d_out, int out_size, void* d_ws, size_t ws_size,
                              hipStream_t stream) {
    const float* g = (const float*)d_in[0];
    const float* h = (const float*)d_in[1];
    const float* W_top = (const float*)d_in[2];
    const float* b_top = (const float*)d_in[3];
    const float* Wp[4], *bp[4], *Wd[4], *bd[4];
    for (int i = 0; i < 4; ++i) {
        Wp[i] = (const float*)d_in[4 + 4 * i];
        bp[i] = (const float*)d_in[5 + 4 * i];
        Wd[i] = (const float*)d_in[6 + 4 * i];
        bd[i] = (const float*)d_in[7 + 4 * i];
    }
    float* out = (float*)d_out;

    unsigned* wsu = (unsigned*)d_ws;
    unsigned* MA = wsu + 0;       // 500*16
    unsigned* MB = wsu + 8000;    // 400*16
    float* V = (float*)(wsu + 14400);
    int* IDX = (int*)(wsu + 14912);
    float* HSEL = (float*)(wsu + 15424);
    float* RSUM = (float*)(wsu + 15936);

    k_dot<<<500, 512, 0, stream>>>(h, W_top, g, V, MA);
    k_top<<<1, 1024, 0, stream>>>(MA, V, b_top, Wp[0], bp[0], IDX, HSEL, out);

    // layer 0: n=500 -> kk=400
    k_twohop<<<100, 256, 0, stream>>>(MA, MB, IDX, RSUM, 500, 400, 16);
    k_mid<<<1, 1024, 0, stream>>>(MB, RSUM, IDX, HSEL, Wd[0], bd[0], Wp[1], bp[1],
                                  out + 500, 400, 300);
    // layer 1: n=400 -> kk=300
    k_twohop<<<75, 256, 0, stream>>>(MB, MA, IDX, RSUM, 400, 300, 13);
    k_mid<<<1, 1024, 0, stream>>>(MA, RSUM, IDX, HSEL, Wd[1], bd[1], Wp[2], bp[2],
                                  out + 900, 300, 200);
    // layer 2: n=300 -> kk=200
    k_twohop<<<50, 256, 0, stream>>>(MA, MB, IDX, RSUM, 300, 200, 10);
    k_mid<<<1, 1024, 0, stream>>>(MB, RSUM, IDX, HSEL, Wd[2], bd[2], Wp[3], bp[3],
                                  out + 1200, 200, 100);
    // layer 3: n=200 -> kk=100
    k_twohop<<<25, 256, 0, stream>>>(MB, MA, IDX, RSUM, 200, 100, 7);
    k_mid<<<1, 1024, 0, stream>>>(MA, RSUM, IDX, HSEL, Wd[3], bd[3], nullptr, nullptr,
                                  out + 1400, 100, 0);
}

// Round 4
// 134.571 us; speedup vs baseline: 1.9994x; 1.0126x over previous
//
#include <hip/hip_runtime.h>
#include <hip/hip_bf16.h>

// Layer sizes: 500 -> 400 -> 300 -> 200 -> 100
// ws layout (u32 words): MA[500*16] @0, MB[400*16] @8000, V @14400,
// IDX @14912, HSEL @15424, RSUM @15936, SH @16448, SC @16960, SU @17472

#define MS 16  // mask row stride in u32 words

// Branchless masked accumulate: bit k of m sign-extended to 0/-1, ANDed with
// the value's bits. Adding +0.0f is exact.
__device__ __forceinline__ float bitsel(unsigned m, int k, float v) {
    int s = ((int)(m << (31 - k))) >> 31;
    return __int_as_float(s & __float_as_int(v));
}

__device__ __forceinline__ float wave_bfly(float v) {
    for (int o = 32; o; o >>= 1) v += __shfl_xor(v, o);
    return v;
}

// V[row] = dot(h[row,:], Wt); MA[row] = bitmask of g row.
__global__ __launch_bounds__(1024) void k_dot(const float* __restrict__ h,
        const float* __restrict__ Wt, const float* __restrict__ g,
        float* __restrict__ V, unsigned* __restrict__ MA) {
    int row = blockIdx.x, t = threadIdx.x;
    const float4* h4 = (const float4*)(h + (size_t)row * 32768);
    const float4* w4 = (const float4*)Wt;
    float acc = 0.f;
#pragma unroll
    for (int j = 0; j < 8; ++j) {
        float4 a = h4[t + 1024 * j], b = w4[t + 1024 * j];
        acc = fmaf(a.x, b.x, fmaf(a.y, b.y, fmaf(a.z, b.z, fmaf(a.w, b.w, acc))));
    }
    acc = wave_bfly(acc);
    __shared__ float red[16];
    if ((t & 63) == 0) red[t >> 6] = acc;
    __syncthreads();
    if (t == 0) {
        float s = 0.f;
        for (int i = 0; i < 16; ++i) s += red[i];
        V[row] = s;
    }
    if (t < 512) {
        float gv = (t < 500) ? g[row * 500 + t] : 0.f;
        unsigned long long bal = __ballot(gv != 0.f);
        if ((t & 63) == 0) {
            int w = t >> 6;
            MA[row * MS + 2 * w] = (unsigned)bal;
            MA[row * MS + 2 * w + 1] = (unsigned)(bal >> 32);
        }
    }
}

// One wave per row: y[r] = f(dot(maskrow(r), x)).
// mode 0: y = relu(acc + c0), also writes out[r].
// mode 1: y = sigmoid(relu(acc*c0 + c1)).
__global__ __launch_bounds__(256) void k_row(const unsigned* __restrict__ M,
        const float* __restrict__ x, const float* __restrict__ c0p,
        const float* __restrict__ c1p, float* __restrict__ y,
        float* __restrict__ out, int mode) {
    __shared__ float sv[512];
    int t = threadIdx.x;
    sv[t] = (t < 500) ? x[t] : 0.f;
    int t2 = t + 256;
    sv[t2] = (t2 < 500) ? x[t2] : 0.f;
    __syncthreads();
    int wid = t >> 6, l = t & 63;
    int r = blockIdx.x * 4 + wid;
    float acc = 0.f;
#pragma unroll
    for (int j = 0; j < 8; ++j) {
        unsigned m = M[r * MS + 2 * j + (l >> 5)];
        acc += bitsel(m, l & 31, sv[64 * j + l]);
    }
    acc = wave_bfly(acc);
    if (l == 0) {
        float res;
        if (mode == 0) {
            res = fmaxf(acc + c0p[0], 0.f);
            out[r] = res;
        } else {
            float xx = fmaxf(acc * c0p[0] + c1p[0], 0.f);
            res = 1.f / (1.f + expf(-xx));
        }
        y[r] = res;
    }
}

// Stable-rank top-400 of the 500 top-level scores.
__global__ __launch_bounds__(512) void k_rank(const float* __restrict__ SC,
        const float* __restrict__ SH, int* __restrict__ IDX,
        float* __restrict__ HSEL) {
    __shared__ float ssc[512];
    int t = threadIdx.x;
    ssc[t] = (t < 500) ? SC[t] : 0.f;
    __syncthreads();
    if (t < 500) {
        float my = ssc[t];
        int r0 = 0, r1 = 0, r2 = 0, r3 = 0;
        for (int j = 0; j < 512; j += 4) {
            float4 v = *(const float4*)(ssc + j);
            r0 += (v.x > my) || (v.x == my && (j + 0) < t);
            r1 += (v.y > my) || (v.y == my && (j + 1) < t);
            r2 += (v.z > my) || (v.z == my && (j + 2) < t);
            r3 += (v.w > my) || (v.w == my && (j + 3) < t);
        }
        int rank = (r0 + r1) + (r2 + r3);
        if (rank < 400) {
            IDX[rank] = t;
            HSEL[rank] = SH[t] * my;
        }
    }
}

// 2-hop connectivity restricted to selected rows/cols; popcount; su vector.
// 4 waves/block, one selected row per wave. grid = kk/4.
__global__ __launch_bounds__(256) void k_twohop(const unsigned* __restrict__ Mcur,
        unsigned* __restrict__ Mnew, const int* __restrict__ IDX,
        const float* __restrict__ HSEL, const float* __restrict__ Wd,
        float* __restrict__ RSUM, float* __restrict__ SU,
        int n, int kk, int Wcur) {
    int wid = threadIdx.x >> 6, lane = threadIdx.x & 63;
    int r = blockIdx.x * 4 + wid;
    int i = IDX[r];
    __shared__ unsigned srow[4][16];
    __shared__ unsigned un2[4][16];
    if (lane < 16) {
        srow[wid][lane] = (lane < Wcur) ? Mcur[i * MS + lane] : 0u;
        un2[wid][lane] = 0u;
    }
    __syncthreads();
    int part = lane >> 4, w = lane & 15;
    if (w < Wcur) {
        unsigned acc = 0;
        for (int k = part; k < n; k += 4) {
            unsigned sel = ((srow[wid][k >> 5] >> (k & 31)) & 1u) ? 0xffffffffu : 0u;
            acc |= Mcur[k * MS + w] & sel;
        }
        atomicOr(&un2[wid][w], acc);
    }
    __syncthreads();
    unsigned long long cnt = 0;
    for (int c0 = 0; c0 < kk; c0 += 64) {
        int c = c0 + lane;
        int ok = 0;
        if (c < kk) {
            int j = IDX[c];
            ok = (un2[wid][j >> 5] >> (j & 31)) & 1;
        }
        unsigned long long bits = __ballot(ok);
        if (lane == 0) {
            Mnew[r * MS + (c0 >> 5)] = (unsigned)bits;
            Mnew[r * MS + (c0 >> 5) + 1] = (unsigned)(bits >> 32);
        }
        cnt += __popcll(bits);
    }
    if (lane == 0) {
        float c = (float)cnt;
        RSUM[r] = c;
        SU[r] = HSEL[r] * Wd[r] / c;
    }
}

// Down-GCN + next-layer scores + top-k, using density: the 2-hop graph is
// ~99.5% dense, so acc_row = total - sum(complement), complement ~2-3 bits.
__global__ __launch_bounds__(1024) void k_mid(const unsigned* __restrict__ M,
        const float* __restrict__ RSUM, const float* __restrict__ SU,
        int* __restrict__ IDX, float* __restrict__ HSEL,
        const float* __restrict__ bd, const float* __restrict__ Wp,
        const float* __restrict__ bp, float* __restrict__ out_seg,
        int kk, int knext) {
    __shared__ float su[512], sh[512], su2[512], ssc[512], rs[512];
    __shared__ unsigned Ms[400 * MS];
    __shared__ float tot[2];
    int t = threadIdx.x;
    int W = (kk + 31) >> 5;
    unsigned lastmask = (1u << (kk & 31)) - 1u;  // kk&31 in {16,12,8,4}
    if (t < 512) { su[t] = 0.f; su2[t] = 0.f; ssc[t] = 0.f; }
    if (t < kk) { su[t] = SU[t]; rs[t] = RSUM[t]; }
    for (int i = t; i < kk * MS; i += 1024) Ms[i] = M[i];
    __syncthreads();
    if (t < 64) {  // deterministic fixed-tree total of su
        float p = 0.f;
#pragma unroll
        for (int j = 0; j < 8; ++j) p += su[t * 8 + j];
        p = wave_bfly(p);
        if (t == 0) tot[0] = p;
    }
    __syncthreads();
    if (t < kk) {
        float corr = 0.f;
        for (int w = 0; w < W; ++w) {
            unsigned inv = ~Ms[t * MS + w];
            if (w == W - 1) inv &= lastmask;
            while (inv) {
                int b = __ffs(inv) - 1;
                inv &= inv - 1;
                corr += su[(w << 5) + b];
            }
        }
        float acc = tot[0] - corr;
        float hv = fmaxf(acc + bd[0], 0.f);
        sh[t] = hv;
        out_seg[t] = hv;
        su2[t] = hv / rs[t];
    }
    __syncthreads();
    if (knext == 0) return;
    if (t < 64) {
        float p = 0.f;
#pragma unroll
        for (int j = 0; j < 8; ++j) p += su2[t * 8 + j];
        p = wave_bfly(p);
        if (t == 0) tot[1] = p;
    }
    __syncthreads();
    if (t < kk) {
        float corr = 0.f;
        for (int w = 0; w < W; ++w) {
            unsigned inv = ~Ms[t * MS + w];
            if (w == W - 1) inv &= lastmask;
            while (inv) {
                int b = __ffs(inv) - 1;
                inv &= inv - 1;
                corr += su2[(w << 5) + b];
            }
        }
        float x = (tot[1] - corr) * Wp[0] + bp[0];
        ssc[t] = 1.f / (1.f + expf(-fmaxf(x, 0.f)));
    }
    __syncthreads();
    if (t < kk) {
        float my = ssc[t];
        int r0 = 0, r1 = 0, r2 = 0, r3 = 0;
        for (int j = 0; j < 512; j += 4) {
            float4 v = *(const float4*)(ssc + j);
            r0 += (v.x > my) || (v.x == my && (j + 0) < t);
            r1 += (v.y > my) || (v.y == my && (j + 1) < t);
            r2 += (v.z > my) || (v.z == my && (j + 2) < t);
            r3 += (v.w > my) || (v.w == my && (j + 3) < t);
        }
        int rank = (r0 + r1) + (r2 + r3);
        if (rank < knext) {
            IDX[rank] = t;
            HSEL[rank] = sh[t] * my;
        }
    }
}

extern "C" void kernel_launch(void* const* d_in, const int* in_sizes, int n_in,
                              void* d_out, int out_size, void* d_ws, size_t ws_size,
                              hipStream_t stream) {
    const float* g = (const float*)d_in[0];
    const float* h = (const float*)d_in[1];
    const float* W_top = (const float*)d_in[2];
    const float* b_top = (const float*)d_in[3];
    const float* Wp[4], *bp[4], *Wd[4], *bd[4];
    for (int i = 0; i < 4; ++i) {
        Wp[i] = (const float*)d_in[4 + 4 * i];
        bp[i] = (const float*)d_in[5 + 4 * i];
        Wd[i] = (const float*)d_in[6 + 4 * i];
        bd[i] = (const float*)d_in[7 + 4 * i];
    }
    float* out = (float*)d_out;

    unsigned* wsu = (unsigned*)d_ws;
    unsigned* MA = wsu + 0;        // 500*16
    unsigned* MB = wsu + 8000;     // 400*16
    float* V = (float*)(wsu + 14400);
    int* IDX = (int*)(wsu + 14912);
    float* HSEL = (float*)(wsu + 15424);
    float* RSUM = (float*)(wsu + 15936);
    float* SH = (float*)(wsu + 16448);
    float* SC = (float*)(wsu + 16960);
    float* SU = (float*)(wsu + 17472);

    k_dot<<<500, 1024, 0, stream>>>(h, W_top, g, V, MA);
    k_row<<<125, 256, 0, stream>>>(MA, V, b_top, nullptr, SH, out, 0);
    k_row<<<125, 256, 0, stream>>>(MA, SH, Wp[0], bp[0], SC, nullptr, 1);
    k_rank<<<1, 512, 0, stream>>>(SC, SH, IDX, HSEL);

    // layer 0: n=500 -> kk=400
    k_twohop<<<100, 256, 0, stream>>>(MA, MB, IDX, HSEL, Wd[0], RSUM, SU, 500, 400, 16);
    k_mid<<<1, 1024, 0, stream>>>(MB, RSUM, SU, IDX, HSEL, bd[0], Wp[1], bp[1],
                                  out + 500, 400, 300);
    // layer 1: n=400 -> kk=300
    k_twohop<<<75, 256, 0, stream>>>(MB, MA, IDX, HSEL, Wd[1], RSUM, SU, 400, 300, 13);
    k_mid<<<1, 1024, 0, stream>>>(MA, RSUM, SU, IDX, HSEL, bd[1], Wp[2], bp[2],
                                  out + 900, 300, 200);
    // layer 2: n=300 -> kk=200
    k_twohop<<<50, 256, 0, stream>>>(MA, MB, IDX, HSEL, Wd[2], RSUM, SU, 300, 200, 10);
    k_mid<<<1, 1024, 0, stream>>>(MB, RSUM, SU, IDX, HSEL, bd[2], Wp[3], bp[3],
                                  out + 1200, 200, 100);
    // layer 3: n=200 -> kk=100
    k_twohop<<<25, 256, 0, stream>>>(MB, MA, IDX, HSEL, Wd[3], RSUM, SU, 200, 100, 7);
    k_mid<<<1, 1024, 0, stream>>>(MA, RSUM, SU, IDX, HSEL, bd[3], nullptr, nullptr,
                                  out + 1400, 100, 0);
}